// Round 1
// baseline (402.756 us; speedup 1.0000x reference)
//
#include <hip/hip_runtime.h>
#include <hip/hip_bf16.h>
#include <math.h>

typedef __attribute__((ext_vector_type(8))) __bf16 bf16x8;
typedef __attribute__((ext_vector_type(4))) float f32x4;

#define BM 128
#define BN 128
#define BK 32
#define TEMP_INV 14.2857142857142857f   // 1/0.07

// ---- round-to-nearest-even f32 -> bf16 (inputs finite; no NaN path needed)
static __device__ inline unsigned short f2bf(float f) {
  unsigned u = __builtin_bit_cast(unsigned, f);
  u += 0x7fffu + ((u >> 16) & 1u);
  return (unsigned short)(u >> 16);
}

// ---- async global->LDS, 16B per lane
static __device__ inline void async16(const void* g, void* l) {
  __builtin_amdgcn_global_load_lds(
      (const __attribute__((address_space(1))) unsigned int*)g,
      (__attribute__((address_space(3))) unsigned int*)l,
      16, 0, 0);
}

// ============================================================
// Kernel 1: L2-normalize one row (D=1024) and emit bf16
// one block of 256 threads per row; each thread owns 4 floats
// ============================================================
__global__ __launch_bounds__(256) void normalize_rows(
    const float* __restrict__ in, unsigned short* __restrict__ out, int D) {
  const int row = blockIdx.x;
  const int t = threadIdx.x;
  const float4 v = ((const float4*)(in + (size_t)row * D))[t];
  float ss = v.x * v.x + v.y * v.y + v.z * v.z + v.w * v.w;
#pragma unroll
  for (int m = 32; m >= 1; m >>= 1) ss += __shfl_xor(ss, m, 64);
  __shared__ float wsum[4];
  const int wave = t >> 6, lane = t & 63;
  if (lane == 0) wsum[wave] = ss;
  __syncthreads();
  const float tot = wsum[0] + wsum[1] + wsum[2] + wsum[3];
  const float inv = 1.0f / fmaxf(sqrtf(tot), 1e-12f);
  ushort4 o;
  o.x = f2bf(v.x * inv);
  o.y = f2bf(v.y * inv);
  o.z = f2bf(v.z * inv);
  o.w = f2bf(v.w * inv);
  ((ushort4*)(out + (size_t)row * D))[t] = o;
}

// ============================================================
// Kernel 2: fused bf16 MFMA GEMM (A[N,D] x B[M,D]^T) + exp epilogue
// 128x128 tile, BK=32, 4 waves (2x2), 4x4 MFMA tiles of 16x16x32 per wave.
// Epilogue: e = exp(clip(dot/T)), per-row partial sums (pos-masked + total)
// atomically accumulated into pos_acc/neg_acc.
// ============================================================
__global__ __launch_bounds__(256) void infonce_gemm(
    const unsigned short* __restrict__ A, const unsigned short* __restrict__ B,
    const int* __restrict__ la, const int* __restrict__ lb,
    float* __restrict__ pos_acc, float* __restrict__ neg_acc, int D) {
  __shared__ unsigned short sA[BM * BK];  // 8 KB
  __shared__ unsigned short sB[BN * BK];  // 8 KB

  const int tid = threadIdx.x;
  const int lane = tid & 63;
  const int wave = tid >> 6;
  const int wm = wave >> 1;  // 0..1
  const int wn = wave & 1;   // 0..1
  const int row0 = blockIdx.y * BM;
  const int col0 = blockIdx.x * BN;

  // staging map: thread t -> LDS bytes [t*16) ; elem = t*8 (+2048 for 2nd half)
  // elem e -> r = e/32 (= t/4 [+64]), c = e%32 (= (t%4)*8)
  const int sr = tid >> 2;
  const int sc = (tid & 3) * 8;
  const unsigned short* gA0 = A + (size_t)(row0 + sr) * D + sc;
  const unsigned short* gA1 = A + (size_t)(row0 + 64 + sr) * D + sc;
  const unsigned short* gB0 = B + (size_t)(col0 + sr) * D + sc;
  const unsigned short* gB1 = B + (size_t)(col0 + 64 + sr) * D + sc;

  f32x4 acc[4][4] = {};

  const int q = lane >> 4;    // 0..3
  const int l15 = lane & 15;  // 0..15

  for (int k0 = 0; k0 < D; k0 += BK) {
    async16(gA0 + k0, &sA[tid * 8]);
    async16(gA1 + k0, &sA[2048 + tid * 8]);
    async16(gB0 + k0, &sB[tid * 8]);
    async16(gB1 + k0, &sB[2048 + tid * 8]);
    __syncthreads();  // drains vmcnt for global_load_lds

    bf16x8 af[4], bfv[4];
#pragma unroll
    for (int i = 0; i < 4; i++) {
      af[i] = *(const bf16x8*)&sA[(wm * 64 + i * 16 + l15) * BK + q * 8];
      bfv[i] = *(const bf16x8*)&sB[(wn * 64 + i * 16 + l15) * BK + q * 8];
    }
#pragma unroll
    for (int i = 0; i < 4; i++)
#pragma unroll
      for (int j = 0; j < 4; j++)
        acc[i][j] = __builtin_amdgcn_mfma_f32_16x16x32_bf16(af[i], bfv[j], acc[i][j], 0, 0, 0);
    __syncthreads();
  }

  // ---- epilogue: C/D layout col = lane&15, row = quad*4 + reg
  int lbv[4];
#pragma unroll
  for (int j = 0; j < 4; j++) lbv[j] = lb[col0 + wn * 64 + j * 16 + l15];

#pragma unroll
  for (int i = 0; i < 4; i++) {
#pragma unroll
    for (int r = 0; r < 4; r++) {
      const int row = row0 + wm * 64 + i * 16 + q * 4 + r;
      const int lav = la[row];
      float sneg = 0.f, spos = 0.f;
#pragma unroll
      for (int j = 0; j < 4; j++) {
        float s = acc[i][j][r] * TEMP_INV;
        s = fminf(fmaxf(s, -50.f), 50.f);
        const float e = __expf(s);
        sneg += e;
        if (lav == lbv[j]) spos += e;
      }
      // reduce over the 16 lanes of this quad (cols 0..15 of the tiles)
#pragma unroll
      for (int m = 8; m >= 1; m >>= 1) {
        sneg += __shfl_xor(sneg, m, 16);
        spos += __shfl_xor(spos, m, 16);
      }
      if (l15 == 0) {
        atomicAdd(&neg_acc[row], sneg);
        atomicAdd(&pos_acc[row], spos);
      }
    }
  }
}

// ============================================================
// Kernel 3: loss = mean( log(neg) - log(max(pos,1e-8)) )
// ============================================================
__global__ __launch_bounds__(256) void final_reduce(
    const float* __restrict__ pos, const float* __restrict__ neg,
    float* __restrict__ out, int N) {
  double local = 0.0;
  for (int i = threadIdx.x; i < N; i += 256) {
    const float p = fmaxf(pos[i], 1e-8f);
    local += (double)(logf(neg[i]) - logf(p));
  }
#pragma unroll
  for (int m = 32; m >= 1; m >>= 1) local += __shfl_xor(local, m, 64);
  __shared__ double wsum[4];
  const int wave = threadIdx.x >> 6, lane = threadIdx.x & 63;
  if (lane == 0) wsum[wave] = local;
  __syncthreads();
  if (threadIdx.x == 0) {
    const double t = wsum[0] + wsum[1] + wsum[2] + wsum[3];
    out[0] = (float)(t / (double)N);
  }
}

extern "C" void kernel_launch(void* const* d_in, const int* in_sizes, int n_in,
                              void* d_out, int out_size, void* d_ws, size_t ws_size,
                              hipStream_t stream) {
  const float* fa = (const float*)d_in[0];
  const float* fb = (const float*)d_in[1];
  const int* la = (const int*)d_in[2];
  const int* lb = (const int*)d_in[3];

  const int D = 1024;
  const int N = in_sizes[0] / D;  // 8192
  const int M = in_sizes[1] / D;  // 8192

  unsigned short* nA = (unsigned short*)d_ws;
  unsigned short* nB = nA + (size_t)N * D;
  float* pos = (float*)(nB + (size_t)M * D);
  float* neg = pos + N;

  normalize_rows<<<N, 256, 0, stream>>>(fa, nA, D);
  normalize_rows<<<M, 256, 0, stream>>>(fb, nB, D);
  hipMemsetAsync(pos, 0, (size_t)2 * N * sizeof(float), stream);

  dim3 grid(M / BN, N / BM);
  infonce_gemm<<<grid, 256, 0, stream>>>(nA, nB, la, lb, pos, neg, D);

  final_reduce<<<1, 256, 0, stream>>>(pos, neg, (float*)d_out, N);
}

// Round 2
// 370.056 us; speedup vs baseline: 1.0884x; 1.0884x over previous
//
#include <hip/hip_runtime.h>
#include <hip/hip_bf16.h>
#include <math.h>

typedef __attribute__((ext_vector_type(8))) __bf16 bf16x8;
typedef __attribute__((ext_vector_type(4))) float f32x4;

#define BM 128
#define BN 128
#define BK 32
#define TEMP_INV 14.2857142857142857f   // 1/0.07

// ---- round-to-nearest-even f32 -> bf16 (inputs finite; no NaN path needed)
static __device__ inline unsigned short f2bf(float f) {
  unsigned u = __builtin_bit_cast(unsigned, f);
  u += 0x7fffu + ((u >> 16) & 1u);
  return (unsigned short)(u >> 16);
}

// ---- async global->LDS, 16B per lane
static __device__ inline void async16(const void* g, void* l) {
  __builtin_amdgcn_global_load_lds(
      (const __attribute__((address_space(1))) unsigned int*)g,
      (__attribute__((address_space(3))) unsigned int*)l,
      16, 0, 0);
}

// ============================================================
// Kernel 1: L2-normalize rows of A and B (D=1024), emit bf16.
// grid = N + M blocks; block 256 threads; each thread owns 4 floats.
// ============================================================
__global__ __launch_bounds__(256) void normalize_rows(
    const float* __restrict__ a, const float* __restrict__ b,
    unsigned short* __restrict__ oa, unsigned short* __restrict__ ob,
    int N, int D) {
  const int blk = blockIdx.x;
  const float* in;
  unsigned short* out;
  if (blk < N) {
    in = a + (size_t)blk * D;
    out = oa + (size_t)blk * D;
  } else {
    in = b + (size_t)(blk - N) * D;
    out = ob + (size_t)(blk - N) * D;
  }
  const int t = threadIdx.x;
  const float4 v = ((const float4*)in)[t];
  float ss = v.x * v.x + v.y * v.y + v.z * v.z + v.w * v.w;
#pragma unroll
  for (int m = 32; m >= 1; m >>= 1) ss += __shfl_xor(ss, m, 64);
  __shared__ float wsum[4];
  const int wave = t >> 6, lane = t & 63;
  if (lane == 0) wsum[wave] = ss;
  __syncthreads();
  const float tot = wsum[0] + wsum[1] + wsum[2] + wsum[3];
  const float inv = 1.0f / fmaxf(sqrtf(tot), 1e-12f);
  ushort4 o;
  o.x = f2bf(v.x * inv);
  o.y = f2bf(v.y * inv);
  o.z = f2bf(v.z * inv);
  o.w = f2bf(v.w * inv);
  ((ushort4*)out)[t] = o;
}

// ============================================================
// Kernel 2: fused bf16 MFMA GEMM (A[N,D] x B[M,D]^T) + exp epilogue.
// 128x128 tile, BK=32, DOUBLE-BUFFERED LDS, one barrier per K-iter:
//   barrier -> prefetch(k+1, other buf) -> compute(k, this buf)
// prefetch gets the whole compute phase to land before the next
// barrier's implicit vmcnt(0) drain.
// ============================================================
__global__ __launch_bounds__(256) void infonce_gemm(
    const unsigned short* __restrict__ A, const unsigned short* __restrict__ B,
    const int* __restrict__ la, const int* __restrict__ lb,
    float* __restrict__ pos_acc, float* __restrict__ neg_acc, int D) {
  __shared__ unsigned short sA[2][BM * BK];  // 2 x 8 KB
  __shared__ unsigned short sB[2][BN * BK];  // 2 x 8 KB

  const int tid = threadIdx.x;
  const int lane = tid & 63;
  const int wave = tid >> 6;
  const int wm = wave >> 1;  // 0..1
  const int wn = wave & 1;   // 0..1
  const int row0 = blockIdx.y * BM;
  const int col0 = blockIdx.x * BN;

  // staging map: thread t -> LDS bytes [t*16); elem e = t*8 (+2048 2nd half)
  // e -> r = e/32, c = e%32
  const int sr = tid >> 2;
  const int sc = (tid & 3) * 8;
  const unsigned short* gA0 = A + (size_t)(row0 + sr) * D + sc;
  const unsigned short* gA1 = A + (size_t)(row0 + 64 + sr) * D + sc;
  const unsigned short* gB0 = B + (size_t)(col0 + sr) * D + sc;
  const unsigned short* gB1 = B + (size_t)(col0 + 64 + sr) * D + sc;

  f32x4 acc[4][4] = {};

  const int q = lane >> 4;    // 0..3
  const int l15 = lane & 15;  // 0..15

#define STAGE(bufi, kk)                                  \
  do {                                                   \
    async16(gA0 + (kk), &sA[bufi][tid * 8]);             \
    async16(gA1 + (kk), &sA[bufi][2048 + tid * 8]);      \
    async16(gB0 + (kk), &sB[bufi][tid * 8]);             \
    async16(gB1 + (kk), &sB[bufi][2048 + tid * 8]);      \
  } while (0)

#define COMPUTE(bufi)                                                          \
  do {                                                                         \
    bf16x8 af[4], bfv[4];                                                      \
    _Pragma("unroll") for (int i = 0; i < 4; i++) {                            \
      af[i] = *(const bf16x8*)&sA[bufi][(wm * 64 + i * 16 + l15) * BK + q * 8]; \
      bfv[i] = *(const bf16x8*)&sB[bufi][(wn * 64 + i * 16 + l15) * BK + q * 8];\
    }                                                                          \
    _Pragma("unroll") for (int i = 0; i < 4; i++)                              \
        _Pragma("unroll") for (int j = 0; j < 4; j++)                          \
            acc[i][j] =                                                        \
        __builtin_amdgcn_mfma_f32_16x16x32_bf16(af[i], bfv[j], acc[i][j], 0, 0, 0); \
  } while (0)

  STAGE(0, 0);
#pragma unroll 1
  for (int k0 = 0; k0 < D; k0 += 2 * BK) {
    __syncthreads();  // drains vmcnt: tile(k0) is in buf 0; buf 1 free
    if (k0 + BK < D) STAGE(1, k0 + BK);
    COMPUTE(0);
    __syncthreads();  // drains vmcnt: tile(k0+BK) in buf 1; buf 0 free
    if (k0 + 2 * BK < D) STAGE(0, k0 + 2 * BK);
    COMPUTE(1);
  }

  // ---- epilogue: C/D layout col = lane&15, row = quad*4 + reg
  int lbv[4];
#pragma unroll
  for (int j = 0; j < 4; j++) lbv[j] = lb[col0 + wn * 64 + j * 16 + l15];

#pragma unroll
  for (int i = 0; i < 4; i++) {
#pragma unroll
    for (int r = 0; r < 4; r++) {
      const int row = row0 + wm * 64 + i * 16 + q * 4 + r;
      const int lav = la[row];
      float sneg = 0.f, spos = 0.f;
#pragma unroll
      for (int j = 0; j < 4; j++) {
        float s = acc[i][j][r] * TEMP_INV;
        s = fminf(fmaxf(s, -50.f), 50.f);
        const float e = __expf(s);
        sneg += e;
        if (lav == lbv[j]) spos += e;
      }
      // reduce over the 16 lanes of this quad (cols 0..15 of the tiles)
#pragma unroll
      for (int m = 8; m >= 1; m >>= 1) {
        sneg += __shfl_xor(sneg, m, 16);
        spos += __shfl_xor(spos, m, 16);
      }
      if (l15 == 0) {
        atomicAdd(&neg_acc[row], sneg);
        atomicAdd(&pos_acc[row], spos);
      }
    }
  }
}

// ============================================================
// Kernel 3: loss = mean( log(neg) - log(max(pos,1e-8)) )
// ============================================================
__global__ __launch_bounds__(256) void final_reduce(
    const float* __restrict__ pos, const float* __restrict__ neg,
    float* __restrict__ out, int N) {
  double local = 0.0;
  for (int i = threadIdx.x; i < N; i += 256) {
    const float p = fmaxf(pos[i], 1e-8f);
    local += (double)(logf(neg[i]) - logf(p));
  }
#pragma unroll
  for (int m = 32; m >= 1; m >>= 1) local += __shfl_xor(local, m, 64);
  __shared__ double wsum[4];
  const int wave = threadIdx.x >> 6, lane = threadIdx.x & 63;
  if (lane == 0) wsum[wave] = local;
  __syncthreads();
  if (threadIdx.x == 0) {
    const double t = wsum[0] + wsum[1] + wsum[2] + wsum[3];
    out[0] = (float)(t / (double)N);
  }
}

extern "C" void kernel_launch(void* const* d_in, const int* in_sizes, int n_in,
                              void* d_out, int out_size, void* d_ws, size_t ws_size,
                              hipStream_t stream) {
  const float* fa = (const float*)d_in[0];
  const float* fb = (const float*)d_in[1];
  const int* la = (const int*)d_in[2];
  const int* lb = (const int*)d_in[3];

  const int D = 1024;
  const int N = in_sizes[0] / D;  // 8192
  const int M = in_sizes[1] / D;  // 8192

  unsigned short* nA = (unsigned short*)d_ws;
  unsigned short* nB = nA + (size_t)N * D;
  float* pos = (float*)(nB + (size_t)M * D);
  float* neg = pos + N;

  normalize_rows<<<N + M, 256, 0, stream>>>(fa, fb, nA, nB, N, D);
  hipMemsetAsync(pos, 0, (size_t)2 * N * sizeof(float), stream);

  dim3 grid(M / BN, N / BM);
  infonce_gemm<<<grid, 256, 0, stream>>>(nA, nB, la, lb, pos, neg, D);

  final_reduce<<<1, 256, 0, stream>>>(pos, neg, (float*)d_out, N);
}

// Round 3
// 342.932 us; speedup vs baseline: 1.1744x; 1.0791x over previous
//
#include <hip/hip_runtime.h>
#include <hip/hip_bf16.h>
#include <math.h>

typedef __attribute__((ext_vector_type(4))) float f32x4;

#define BM 128
#define BN 128
#define BK 32
#define TEMP_INV 14.2857142857142857f   // 1/0.07

// ---- async global->LDS, 16B per lane
static __device__ inline void async16(const void* g, void* l) {
  __builtin_amdgcn_global_load_lds(
      (const __attribute__((address_space(1))) unsigned int*)g,
      (__attribute__((address_space(3))) unsigned int*)l,
      16, 0, 0);
}

// ============================================================
// Kernel 1: L2-normalize rows of A and B (D=1024), emit fp8 e4m3.
// grid = N + M blocks; block 256 threads; each thread owns 4 floats.
// ============================================================
__global__ __launch_bounds__(256) void normalize_rows(
    const float* __restrict__ a, const float* __restrict__ b,
    unsigned char* __restrict__ oa, unsigned char* __restrict__ ob,
    int N, int D) {
  const int blk = blockIdx.x;
  const float* in;
  unsigned char* out;
  if (blk < N) {
    in = a + (size_t)blk * D;
    out = oa + (size_t)blk * D;
  } else {
    in = b + (size_t)(blk - N) * D;
    out = ob + (size_t)(blk - N) * D;
  }
  const int t = threadIdx.x;
  const float4 v = ((const float4*)in)[t];
  float ss = v.x * v.x + v.y * v.y + v.z * v.z + v.w * v.w;
#pragma unroll
  for (int m = 32; m >= 1; m >>= 1) ss += __shfl_xor(ss, m, 64);
  __shared__ float wsum[4];
  const int wave = t >> 6, lane = t & 63;
  if (lane == 0) wsum[wave] = ss;
  __syncthreads();
  const float tot = wsum[0] + wsum[1] + wsum[2] + wsum[3];
  const float inv = 1.0f / fmaxf(sqrtf(tot), 1e-12f);
  // pack 4 x fp8 e4m3 (OCP) into one dword
  int r = __builtin_amdgcn_cvt_pk_fp8_f32(v.x * inv, v.y * inv, 0, false);
  r = __builtin_amdgcn_cvt_pk_fp8_f32(v.z * inv, v.w * inv, r, true);
  ((int*)out)[t] = r;
}

// ============================================================
// Kernel 2: fused fp8 MFMA GEMM (A[N,D] x B[M,D]^T) + exp epilogue.
// 128x128 tile, BK=32, double-buffered LDS, one barrier per K-iter.
// 16x16x32_fp8_fp8 MFMA: i64 fragments (8 fp8/lane), same C/D layout
// as the bf16 variant (dtype-independent, verified).
// __launch_bounds__(256,4): force <=128 regs -> 4 blocks/CU.
// ============================================================
__global__ __launch_bounds__(256, 4) void infonce_gemm(
    const unsigned char* __restrict__ A, const unsigned char* __restrict__ B,
    const int* __restrict__ la, const int* __restrict__ lb,
    float* __restrict__ pos_acc, float* __restrict__ neg_acc, int D) {
  __shared__ unsigned char sA[2][BM * BK];  // 2 x 4 KB
  __shared__ unsigned char sB[2][BN * BK];  // 2 x 4 KB

  const int tid = threadIdx.x;
  const int lane = tid & 63;
  const int wave = tid >> 6;
  const int wm = wave >> 1;  // 0..1
  const int wn = wave & 1;   // 0..1
  const int row0 = blockIdx.y * BM;
  const int col0 = blockIdx.x * BN;

  // staging map: thread t -> LDS bytes [t*16); elem e = t*16
  // e -> r = e/32 (= t>>1), c = e%32 (= (t&1)*16)
  const int sr = tid >> 1;
  const int sc = (tid & 1) * 16;
  const unsigned char* gA = A + (size_t)(row0 + sr) * D + sc;
  const unsigned char* gB = B + (size_t)(col0 + sr) * D + sc;

  f32x4 acc[4][4] = {};

  const int q = lane >> 4;    // 0..3
  const int l15 = lane & 15;  // 0..15

#define STAGE(bufi, kk)                      \
  do {                                       \
    async16(gA + (kk), &sA[bufi][tid * 16]); \
    async16(gB + (kk), &sB[bufi][tid * 16]); \
  } while (0)

#define COMPUTE(bufi)                                                         \
  do {                                                                        \
    long af[4], bfv[4];                                                       \
    _Pragma("unroll") for (int i = 0; i < 4; i++) {                           \
      af[i] = *(const long*)&sA[bufi][(wm * 64 + i * 16 + l15) * BK + q * 8]; \
      bfv[i] = *(const long*)&sB[bufi][(wn * 64 + i * 16 + l15) * BK + q * 8];\
    }                                                                         \
    _Pragma("unroll") for (int i = 0; i < 4; i++)                             \
        _Pragma("unroll") for (int j = 0; j < 4; j++)                         \
            acc[i][j] = __builtin_amdgcn_mfma_f32_16x16x32_fp8_fp8(           \
                af[i], bfv[j], acc[i][j], 0, 0, 0);                           \
  } while (0)

  STAGE(0, 0);
#pragma unroll 1
  for (int k0 = 0; k0 < D; k0 += 2 * BK) {
    __syncthreads();  // drains vmcnt: tile(k0) in buf 0; buf 1 free
    if (k0 + BK < D) STAGE(1, k0 + BK);
    COMPUTE(0);
    __syncthreads();  // drains vmcnt: tile(k0+BK) in buf 1; buf 0 free
    if (k0 + 2 * BK < D) STAGE(0, k0 + 2 * BK);
    COMPUTE(1);
  }

  // ---- epilogue: C/D layout col = lane&15, row = quad*4 + reg
  int lbv[4];
#pragma unroll
  for (int j = 0; j < 4; j++) lbv[j] = lb[col0 + wn * 64 + j * 16 + l15];

#pragma unroll
  for (int i = 0; i < 4; i++) {
#pragma unroll
    for (int r = 0; r < 4; r++) {
      const int row = row0 + wm * 64 + i * 16 + q * 4 + r;
      const int lav = la[row];
      float sneg = 0.f, spos = 0.f;
#pragma unroll
      for (int j = 0; j < 4; j++) {
        float s = acc[i][j][r] * TEMP_INV;
        s = fminf(fmaxf(s, -50.f), 50.f);
        const float e = __expf(s);
        sneg += e;
        if (lav == lbv[j]) spos += e;
      }
      // reduce over the 16 lanes of this quad (cols 0..15 of the tiles)
#pragma unroll
      for (int m = 8; m >= 1; m >>= 1) {
        sneg += __shfl_xor(sneg, m, 16);
        spos += __shfl_xor(spos, m, 16);
      }
      if (l15 == 0) {
        atomicAdd(&neg_acc[row], sneg);
        atomicAdd(&pos_acc[row], spos);
      }
    }
  }
}

// ============================================================
// Kernel 3: loss = mean( log(neg) - log(max(pos,1e-8)) )
// ============================================================
__global__ __launch_bounds__(256) void final_reduce(
    const float* __restrict__ pos, const float* __restrict__ neg,
    float* __restrict__ out, int N) {
  double local = 0.0;
  for (int i = threadIdx.x; i < N; i += 256) {
    const float p = fmaxf(pos[i], 1e-8f);
    local += (double)(logf(neg[i]) - logf(p));
  }
#pragma unroll
  for (int m = 32; m >= 1; m >>= 1) local += __shfl_xor(local, m, 64);
  __shared__ double wsum[4];
  const int wave = threadIdx.x >> 6, lane = threadIdx.x & 63;
  if (lane == 0) wsum[wave] = local;
  __syncthreads();
  if (threadIdx.x == 0) {
    const double t = wsum[0] + wsum[1] + wsum[2] + wsum[3];
    out[0] = (float)(t / (double)N);
  }
}

extern "C" void kernel_launch(void* const* d_in, const int* in_sizes, int n_in,
                              void* d_out, int out_size, void* d_ws, size_t ws_size,
                              hipStream_t stream) {
  const float* fa = (const float*)d_in[0];
  const float* fb = (const float*)d_in[1];
  const int* la = (const int*)d_in[2];
  const int* lb = (const int*)d_in[3];

  const int D = 1024;
  const int N = in_sizes[0] / D;  // 8192
  const int M = in_sizes[1] / D;  // 8192

  unsigned char* nA = (unsigned char*)d_ws;
  unsigned char* nB = nA + (size_t)N * D;
  float* pos = (float*)(nB + (size_t)M * D);
  float* neg = pos + N;

  normalize_rows<<<N + M, 256, 0, stream>>>(fa, fb, nA, nB, N, D);
  hipMemsetAsync(pos, 0, (size_t)2 * N * sizeof(float), stream);

  dim3 grid(M / BN, N / BM);
  infonce_gemm<<<grid, 256, 0, stream>>>(nA, nB, la, lb, pos, neg, D);

  final_reduce<<<1, 256, 0, stream>>>(pos, neg, (float*)d_out, N);
}

// Round 4
// 315.810 us; speedup vs baseline: 1.2753x; 1.0859x over previous
//
#include <hip/hip_runtime.h>
#include <hip/hip_bf16.h>
#include <math.h>

typedef __attribute__((ext_vector_type(4))) float f32x4;

#define BM 128
#define BN 128
#define BK 32
#define TEMP_INV 14.2857142857142857f   // 1/0.07

// ---- async global->LDS, 16B per lane
static __device__ inline void async16(const void* g, void* l) {
  __builtin_amdgcn_global_load_lds(
      (const __attribute__((address_space(1))) unsigned int*)g,
      (__attribute__((address_space(3))) unsigned int*)l,
      16, 0, 0);
}

// ============================================================
// Kernel 1: L2-normalize rows of A and B (D=1024), emit fp8 e4m3.
// grid = N + M blocks; block 256 threads; each thread owns 4 floats.
// ============================================================
__global__ __launch_bounds__(256) void normalize_rows(
    const float* __restrict__ a, const float* __restrict__ b,
    unsigned char* __restrict__ oa, unsigned char* __restrict__ ob,
    int N, int D) {
  const int blk = blockIdx.x;
  const float* in;
  unsigned char* out;
  if (blk < N) {
    in = a + (size_t)blk * D;
    out = oa + (size_t)blk * D;
  } else {
    in = b + (size_t)(blk - N) * D;
    out = ob + (size_t)(blk - N) * D;
  }
  const int t = threadIdx.x;
  const float4 v = ((const float4*)in)[t];
  float ss = v.x * v.x + v.y * v.y + v.z * v.z + v.w * v.w;
#pragma unroll
  for (int m = 32; m >= 1; m >>= 1) ss += __shfl_xor(ss, m, 64);
  __shared__ float wsum[4];
  const int wave = t >> 6, lane = t & 63;
  if (lane == 0) wsum[wave] = ss;
  __syncthreads();
  const float tot = wsum[0] + wsum[1] + wsum[2] + wsum[3];
  const float inv = 1.0f / fmaxf(sqrtf(tot), 1e-12f);
  // pack 4 x fp8 e4m3 (OCP) into one dword
  int r = __builtin_amdgcn_cvt_pk_fp8_f32(v.x * inv, v.y * inv, 0, false);
  r = __builtin_amdgcn_cvt_pk_fp8_f32(v.z * inv, v.w * inv, r, true);
  ((int*)out)[t] = r;
}

// ============================================================
// Kernel 2: fused fp8 MFMA GEMM (A[N,D] x B[M,D]^T) + exp epilogue.
// 128x128 tile, BK=32, double-buffered LDS, one barrier per K-iter.
//
// LDS XOR swizzle (bank-conflict fix): a 128x32B tile is 256 chunks of
// 16B. Chunk (row r, half h) lives at slot 2r + (h ^ ((r>>2)&1)).
//  - staging: lane t writes slot t -> fetches row t>>1,
//    half (t&1) ^ ((t>>3)&1)  (global reads stay 16B coalesced)
//  - compute: lane reads b64 at r*32 + ((q>>1)^((l15>>2)&1))*16 + (q&1)*8.
//    Bank math: each 8-bank group serves its 16 lanes as 4 lanes/dword-pair
//    = the wave64-b64 structural minimum (was 4-way same-bank serialize).
//    Swizzle bit depends only on l15 -> loop-invariant, no inner-loop VALU.
// ============================================================
__global__ __launch_bounds__(256, 4) void infonce_gemm(
    const unsigned char* __restrict__ A, const unsigned char* __restrict__ B,
    const int* __restrict__ la, const int* __restrict__ lb,
    float* __restrict__ pos_acc, float* __restrict__ neg_acc, int D) {
  __shared__ unsigned char sA[2][BM * BK];  // 2 x 4 KB
  __shared__ unsigned char sB[2][BN * BK];  // 2 x 4 KB

  const int tid = threadIdx.x;
  const int lane = tid & 63;
  const int wave = tid >> 6;
  const int wm = wave >> 1;  // 0..1
  const int wn = wave & 1;   // 0..1
  const int row0 = blockIdx.y * BM;
  const int col0 = blockIdx.x * BN;

  // staging map with XOR swizzle: lane t -> row t>>1, 16B-half (t&1)^((t>>3)&1)
  const int sr = tid >> 1;
  const int sc = ((tid & 1) ^ ((tid >> 3) & 1)) * 16;
  const unsigned char* gA = A + (size_t)(row0 + sr) * D + sc;
  const unsigned char* gB = B + (size_t)(col0 + sr) * D + sc;

  f32x4 acc[4][4] = {};

  const int q = lane >> 4;    // 0..3
  const int l15 = lane & 15;  // 0..15
  // swizzled, loop-invariant inner offset within a 32B row
  const int inn = (((q >> 1) ^ ((l15 >> 2) & 1)) * 16) + (q & 1) * 8;

#define STAGE(bufi, kk)                      \
  do {                                       \
    async16(gA + (kk), &sA[bufi][tid * 16]); \
    async16(gB + (kk), &sB[bufi][tid * 16]); \
  } while (0)

#define COMPUTE(bufi)                                                          \
  do {                                                                         \
    long af[4], bfv[4];                                                        \
    _Pragma("unroll") for (int i = 0; i < 4; i++) {                            \
      af[i] = *(const long*)&sA[bufi][(wm * 64 + i * 16 + l15) * BK + inn];    \
      bfv[i] = *(const long*)&sB[bufi][(wn * 64 + i * 16 + l15) * BK + inn];   \
    }                                                                          \
    _Pragma("unroll") for (int i = 0; i < 4; i++)                              \
        _Pragma("unroll") for (int j = 0; j < 4; j++)                          \
            acc[i][j] = __builtin_amdgcn_mfma_f32_16x16x32_fp8_fp8(            \
                af[i], bfv[j], acc[i][j], 0, 0, 0);                            \
  } while (0)

  STAGE(0, 0);
#pragma unroll 1
  for (int k0 = 0; k0 < D; k0 += 2 * BK) {
    __syncthreads();  // drains vmcnt: tile(k0) in buf 0; buf 1 free
    if (k0 + BK < D) STAGE(1, k0 + BK);
    COMPUTE(0);
    __syncthreads();  // drains vmcnt: tile(k0+BK) in buf 1; buf 0 free
    if (k0 + 2 * BK < D) STAGE(0, k0 + 2 * BK);
    COMPUTE(1);
  }

  // ---- epilogue: C/D layout col = lane&15, row = quad*4 + reg
  int lbv[4];
#pragma unroll
  for (int j = 0; j < 4; j++) lbv[j] = lb[col0 + wn * 64 + j * 16 + l15];

#pragma unroll
  for (int i = 0; i < 4; i++) {
#pragma unroll
    for (int r = 0; r < 4; r++) {
      const int row = row0 + wm * 64 + i * 16 + q * 4 + r;
      const int lav = la[row];
      float sneg = 0.f, spos = 0.f;
#pragma unroll
      for (int j = 0; j < 4; j++) {
        float s = acc[i][j][r] * TEMP_INV;
        s = fminf(fmaxf(s, -50.f), 50.f);
        const float e = __expf(s);
        sneg += e;
        if (lav == lbv[j]) spos += e;
      }
      // reduce over the 16 lanes of this quad (cols 0..15 of the tiles)
#pragma unroll
      for (int m = 8; m >= 1; m >>= 1) {
        sneg += __shfl_xor(sneg, m, 16);
        spos += __shfl_xor(spos, m, 16);
      }
      if (l15 == 0) {
        atomicAdd(&neg_acc[row], sneg);
        atomicAdd(&pos_acc[row], spos);
      }
    }
  }
}

// ============================================================
// Kernel 3: loss = mean( log(neg) - log(max(pos,1e-8)) )
// ============================================================
__global__ __launch_bounds__(256) void final_reduce(
    const float* __restrict__ pos, const float* __restrict__ neg,
    float* __restrict__ out, int N) {
  double local = 0.0;
  for (int i = threadIdx.x; i < N; i += 256) {
    const float p = fmaxf(pos[i], 1e-8f);
    local += (double)(logf(neg[i]) - logf(p));
  }
#pragma unroll
  for (int m = 32; m >= 1; m >>= 1) local += __shfl_xor(local, m, 64);
  __shared__ double wsum[4];
  const int wave = threadIdx.x >> 6, lane = threadIdx.x & 63;
  if (lane == 0) wsum[wave] = local;
  __syncthreads();
  if (threadIdx.x == 0) {
    const double t = wsum[0] + wsum[1] + wsum[2] + wsum[3];
    out[0] = (float)(t / (double)N);
  }
}

extern "C" void kernel_launch(void* const* d_in, const int* in_sizes, int n_in,
                              void* d_out, int out_size, void* d_ws, size_t ws_size,
                              hipStream_t stream) {
  const float* fa = (const float*)d_in[0];
  const float* fb = (const float*)d_in[1];
  const int* la = (const int*)d_in[2];
  const int* lb = (const int*)d_in[3];

  const int D = 1024;
  const int N = in_sizes[0] / D;  // 8192
  const int M = in_sizes[1] / D;  // 8192

  unsigned char* nA = (unsigned char*)d_ws;
  unsigned char* nB = nA + (size_t)N * D;
  float* pos = (float*)(nB + (size_t)M * D);
  float* neg = pos + N;

  normalize_rows<<<N + M, 256, 0, stream>>>(fa, fb, nA, nB, N, D);
  hipMemsetAsync(pos, 0, (size_t)2 * N * sizeof(float), stream);

  dim3 grid(M / BN, N / BM);
  infonce_gemm<<<grid, 256, 0, stream>>>(nA, nB, la, lb, pos, neg, D);

  final_reduce<<<1, 256, 0, stream>>>(pos, neg, (float*)d_out, N);
}

// Round 5
// 281.445 us; speedup vs baseline: 1.4310x; 1.1221x over previous
//
#include <hip/hip_runtime.h>
#include <hip/hip_bf16.h>
#include <math.h>

typedef __attribute__((ext_vector_type(4))) float f32x4;
typedef __attribute__((ext_vector_type(2))) long lx2;

#define BM 128
#define BN 128
#define BK 64
#define TEMP_INV 14.2857142857142857f   // 1/0.07

// ---- async global->LDS, 16B per lane
static __device__ inline void async16(const void* g, void* l) {
  __builtin_amdgcn_global_load_lds(
      (const __attribute__((address_space(1))) unsigned int*)g,
      (__attribute__((address_space(3))) unsigned int*)l,
      16, 0, 0);
}

// ============================================================
// Kernel 1: L2-normalize rows of A and B (D=1024), emit fp8 e4m3
// in K-INTERLEAVED layout: within each 64-byte K-group, the eight
// 8B chunks are stored in order [0,4,1,5,2,6,3,7], so that one 16B
// slot p holds chunks (p, p+4) = the lane's K-data for BOTH K-32
// halves of a K-64 MFMA step (enables ds_read_b128 in the GEMM).
// Also zeroes pos/neg accumulators (replaces the memset node).
// ============================================================
__global__ __launch_bounds__(256) void normalize_rows(
    const float* __restrict__ a, const float* __restrict__ b,
    unsigned char* __restrict__ oa, unsigned char* __restrict__ ob,
    float* __restrict__ pos_acc, float* __restrict__ neg_acc,
    int N, int D) {
  const int blk = blockIdx.x;
  const float* in;
  unsigned char* out;
  if (blk < N) {
    in = a + (size_t)blk * D;
    out = oa + (size_t)blk * D;
    if (threadIdx.x == 0) { pos_acc[blk] = 0.f; neg_acc[blk] = 0.f; }
  } else {
    in = b + (size_t)(blk - N) * D;
    out = ob + (size_t)(blk - N) * D;
  }
  const int t = threadIdx.x;
  const float4 v = ((const float4*)in)[t];
  float ss = v.x * v.x + v.y * v.y + v.z * v.z + v.w * v.w;
#pragma unroll
  for (int m = 32; m >= 1; m >>= 1) ss += __shfl_xor(ss, m, 64);
  __shared__ float wsum[4];
  const int wave = t >> 6, lane = t & 63;
  if (lane == 0) wsum[wave] = ss;
  __syncthreads();
  const float tot = wsum[0] + wsum[1] + wsum[2] + wsum[3];
  const float inv = 1.0f / fmaxf(sqrtf(tot), 1e-12f);
  // pack 4 x fp8 e4m3 (OCP) into one dword
  int r = __builtin_amdgcn_cvt_pk_fp8_f32(v.x * inv, v.y * inv, 0, false);
  r = __builtin_amdgcn_cvt_pk_fp8_f32(v.z * inv, v.w * inv, r, true);
  // interleave: thread t's dword is bytes k=4t..4t+3; group g=t>>4,
  // 8B-chunk c=(t>>1)&7, dword-half o=t&1; chunk c -> pos (c&3)*2+(c>>2)
  const int g = t >> 4, c = (t >> 1) & 7, o = t & 1;
  const int outIdx = g * 16 + ((c & 3) * 2 + (c >> 2)) * 2 + o;
  ((int*)out)[outIdx] = r;
}

// ============================================================
// Kernel 2: fused fp8 MFMA GEMM (A[N,D] x B[M,D]^T) + exp epilogue.
// 128x128 tile, BK=64, double-buffered LDS, one barrier per K-iter.
// K-interleaved fp8 layout: lane's frag for a K-64 step is ONE
// contiguous 16B LDS read (ds_read_b128) = (lo 8B -> k-half 0,
// hi 8B -> k-half 1). 16B slots XOR-swizzled by row (slot h of row r
// stored at h ^ (r&3)) -> <=4 lanes per 4-bank group (structural min).
// 16 phases, 8 ds_read_b128 + 32 MFMA per wave per phase.
// ============================================================
__global__ __launch_bounds__(256, 4) void infonce_gemm(
    const unsigned char* __restrict__ A, const unsigned char* __restrict__ B,
    const int* __restrict__ la, const int* __restrict__ lb,
    float* __restrict__ pos_acc, float* __restrict__ neg_acc, int D) {
  __shared__ __align__(16) unsigned char sA[2][BM * BK];  // 2 x 8 KB
  __shared__ __align__(16) unsigned char sB[2][BN * BK];  // 2 x 8 KB

  const int tid = threadIdx.x;
  const int lane = tid & 63;
  const int wave = tid >> 6;
  const int wm = wave >> 1;  // 0..1
  const int wn = wave & 1;   // 0..1
  const int row0 = blockIdx.y * BM;
  const int col0 = blockIdx.x * BN;

  // staging: LDS slot s = tid (+256): row r = s>>2, phys pos p = s&3
  // holds global 16B slot h = p ^ (r&3) of the row's current K-64 group
  const int sr = tid >> 2;
  const int sh = (tid & 3) ^ (sr & 3);
  const unsigned char* gA0 = A + (size_t)(row0 + sr) * D + sh * 16;
  const unsigned char* gA1 = gA0 + (size_t)64 * D;
  const unsigned char* gB0 = B + (size_t)(col0 + sr) * D + sh * 16;
  const unsigned char* gB1 = gB0 + (size_t)64 * D;

  f32x4 acc[4][4] = {};

  const int q = lane >> 4;    // 0..3
  const int l15 = lane & 15;  // 0..15
  // swizzled loop-invariant 16B-slot offset within a row
  const int inn = ((q ^ (l15 & 3)) * 16);

#define STAGE(bufi, kk)                             \
  do {                                              \
    async16(gA0 + (kk), &sA[bufi][tid * 16]);       \
    async16(gA1 + (kk), &sA[bufi][4096 + tid * 16]);\
    async16(gB0 + (kk), &sB[bufi][tid * 16]);       \
    async16(gB1 + (kk), &sB[bufi][4096 + tid * 16]);\
  } while (0)

#define COMPUTE(bufi)                                                         \
  do {                                                                        \
    lx2 bv0 = *(const lx2*)&sB[bufi][(wn * 64 + 0 + l15) * BK + inn];         \
    lx2 bv1 = *(const lx2*)&sB[bufi][(wn * 64 + 16 + l15) * BK + inn];        \
    lx2 bv2 = *(const lx2*)&sB[bufi][(wn * 64 + 32 + l15) * BK + inn];        \
    lx2 bv3 = *(const lx2*)&sB[bufi][(wn * 64 + 48 + l15) * BK + inn];        \
    _Pragma("unroll") for (int i = 0; i < 4; i++) {                           \
      lx2 av = *(const lx2*)&sA[bufi][(wm * 64 + i * 16 + l15) * BK + inn];   \
      acc[i][0] = __builtin_amdgcn_mfma_f32_16x16x32_fp8_fp8(av.x, bv0.x, acc[i][0], 0, 0, 0); \
      acc[i][1] = __builtin_amdgcn_mfma_f32_16x16x32_fp8_fp8(av.x, bv1.x, acc[i][1], 0, 0, 0); \
      acc[i][2] = __builtin_amdgcn_mfma_f32_16x16x32_fp8_fp8(av.x, bv2.x, acc[i][2], 0, 0, 0); \
      acc[i][3] = __builtin_amdgcn_mfma_f32_16x16x32_fp8_fp8(av.x, bv3.x, acc[i][3], 0, 0, 0); \
      acc[i][0] = __builtin_amdgcn_mfma_f32_16x16x32_fp8_fp8(av.y, bv0.y, acc[i][0], 0, 0, 0); \
      acc[i][1] = __builtin_amdgcn_mfma_f32_16x16x32_fp8_fp8(av.y, bv1.y, acc[i][1], 0, 0, 0); \
      acc[i][2] = __builtin_amdgcn_mfma_f32_16x16x32_fp8_fp8(av.y, bv2.y, acc[i][2], 0, 0, 0); \
      acc[i][3] = __builtin_amdgcn_mfma_f32_16x16x32_fp8_fp8(av.y, bv3.y, acc[i][3], 0, 0, 0); \
    }                                                                         \
  } while (0)

  STAGE(0, 0);
#pragma unroll 1
  for (int k0 = 0; k0 < D; k0 += 2 * BK) {
    __syncthreads();  // drains vmcnt: tile(k0) in buf 0; buf 1 free
    if (k0 + BK < D) STAGE(1, k0 + BK);
    COMPUTE(0);
    __syncthreads();  // drains vmcnt: tile(k0+BK) in buf 1; buf 0 free
    if (k0 + 2 * BK < D) STAGE(0, k0 + 2 * BK);
    COMPUTE(1);
  }

  // ---- epilogue: C/D layout col = lane&15, row = quad*4 + reg
  int lbv[4];
#pragma unroll
  for (int j = 0; j < 4; j++) lbv[j] = lb[col0 + wn * 64 + j * 16 + l15];

#pragma unroll
  for (int i = 0; i < 4; i++) {
#pragma unroll
    for (int r = 0; r < 4; r++) {
      const int row = row0 + wm * 64 + i * 16 + q * 4 + r;
      const int lav = la[row];
      float sneg = 0.f, spos = 0.f;
#pragma unroll
      for (int j = 0; j < 4; j++) {
        float s = acc[i][j][r] * TEMP_INV;
        s = fminf(fmaxf(s, -50.f), 50.f);
        const float e = __expf(s);
        sneg += e;
        if (lav == lbv[j]) spos += e;
      }
      // reduce over the 16 lanes of this quad (cols 0..15 of the tiles)
#pragma unroll
      for (int m = 8; m >= 1; m >>= 1) {
        sneg += __shfl_xor(sneg, m, 16);
        spos += __shfl_xor(spos, m, 16);
      }
      if (l15 == 0) {
        atomicAdd(&neg_acc[row], sneg);
        atomicAdd(&pos_acc[row], spos);
      }
    }
  }
}

// ============================================================
// Kernel 3: loss = mean( log(neg) - log(max(pos,1e-8)) )
// 1024 threads, float4 loads -> only 2 latency-serial iterations.
// ============================================================
__global__ __launch_bounds__(1024) void final_reduce(
    const float* __restrict__ pos, const float* __restrict__ neg,
    float* __restrict__ out, int N) {
  double local = 0.0;
  const int t = threadIdx.x;
  for (int i = t; i < N / 4; i += 1024) {
    const float4 p4 = ((const float4*)pos)[i];
    const float4 n4 = ((const float4*)neg)[i];
    local += (double)(logf(n4.x) - logf(fmaxf(p4.x, 1e-8f)));
    local += (double)(logf(n4.y) - logf(fmaxf(p4.y, 1e-8f)));
    local += (double)(logf(n4.z) - logf(fmaxf(p4.z, 1e-8f)));
    local += (double)(logf(n4.w) - logf(fmaxf(p4.w, 1e-8f)));
  }
#pragma unroll
  for (int m = 32; m >= 1; m >>= 1) local += __shfl_xor(local, m, 64);
  __shared__ double wsum[16];
  const int wave = t >> 6, lane = t & 63;
  if (lane == 0) wsum[wave] = local;
  __syncthreads();
  if (t == 0) {
    double tot = 0.0;
#pragma unroll
    for (int w = 0; w < 16; w++) tot += wsum[w];
    out[0] = (float)(tot / (double)N);
  }
}

extern "C" void kernel_launch(void* const* d_in, const int* in_sizes, int n_in,
                              void* d_out, int out_size, void* d_ws, size_t ws_size,
                              hipStream_t stream) {
  const float* fa = (const float*)d_in[0];
  const float* fb = (const float*)d_in[1];
  const int* la = (const int*)d_in[2];
  const int* lb = (const int*)d_in[3];

  const int D = 1024;
  const int N = in_sizes[0] / D;  // 8192
  const int M = in_sizes[1] / D;  // 8192

  unsigned char* nA = (unsigned char*)d_ws;
  unsigned char* nB = nA + (size_t)N * D;
  float* pos = (float*)(nB + (size_t)M * D);
  float* neg = pos + N;

  normalize_rows<<<N + M, 256, 0, stream>>>(fa, fb, nA, nB, pos, neg, N, D);

  dim3 grid(M / BN, N / BM);
  infonce_gemm<<<grid, 256, 0, stream>>>(nA, nB, la, lb, pos, neg, D);

  final_reduce<<<1, 1024, 0, stream>>>(pos, neg, (float*)d_out, N);
}